// Round 1
// baseline (2028.268 us; speedup 1.0000x reference)
//
#include <hip/hip_runtime.h>
#include <stdint.h>

// LSTM autoencoder: B=256,T=256,D=128,H=256, gate order i,f,g,o.
// Phases: cvt/perm prep -> enc xproj GEMM -> enc recurrence (persistent, batch-sliced)
//         -> dec xproj GEMM -> dec recurrence.
// All matmul in bf16 MFMA 16x16x32, fp32 accum. No inter-workgroup sync anywhere.

#define B_N 256
#define T_N 256
#define D_N 128
#define H_N 256

typedef __attribute__((ext_vector_type(8))) short bf16x8;  // MFMA A/B frag (4 VGPRs)
typedef __attribute__((ext_vector_type(4))) float f32x4;   // MFMA C/D frag
typedef unsigned short u16;
typedef unsigned int u32;

__device__ __forceinline__ float bflo(u32 u){ return __uint_as_float(u << 16); }
__device__ __forceinline__ float bfhi(u32 u){ return __uint_as_float(u & 0xffff0000u); }
__device__ __forceinline__ u32 f2bf_bits(float f){ u32 u = __float_as_uint(f); return (u + 0x7fffu + ((u >> 16) & 1u)) >> 16; }
__device__ __forceinline__ u32 pack2(float lo, float hi){ return f2bf_bits(lo) | (f2bf_bits(hi) << 16); }
__device__ __forceinline__ float sigm(float x){ return __builtin_amdgcn_rcpf(1.f + __expf(-x)); }
__device__ __forceinline__ float tanh_f(float x){ return 1.f - 2.f * __builtin_amdgcn_rcpf(1.f + __expf(2.f * x)); }

// ---------- prep kernels ----------
__global__ void k_cvt(const float* __restrict__ src, u16* __restrict__ dst, int n){
  int i = (blockIdx.x * blockDim.x + threadIdx.x) * 4;
  if (i >= n) return;
  float4 v = *(const float4*)(src + i);
  uint2 o; o.x = pack2(v.x, v.y); o.y = pack2(v.z, v.w);
  *(uint2*)(dst + i) = o;
}

// Row permutation p -> orig so that wave v owns rows [v*4U, (v+1)*4U) = {i,f,g,o} x units[v*U,(v+1)*U)
// p = (v << (UB+2)) | (g << UB) | uo  ;  orig = (g << (UB+2)) | (v << UB) | uo    (U = 1<<UB units/wave)
__global__ void k_permW(const float* __restrict__ W, u16* __restrict__ Wp, int K, int UB){
  int p = blockIdx.x;
  int uo = p & ((1 << UB) - 1), g = (p >> UB) & 3, v = p >> (UB + 2);
  int orig = (g << (UB + 2)) | (v << UB) | uo;
  for (int k = threadIdx.x; k < K; k += blockDim.x)
    Wp[(size_t)p * K + k] = (u16)f2bf_bits(W[(size_t)orig * K + k]);
}

__global__ void k_permB(const float* __restrict__ b1, const float* __restrict__ b2,
                        float* __restrict__ bp, int P, int UB){
  for (int p = threadIdx.x; p < P; p += blockDim.x){
    int uo = p & ((1 << UB) - 1), g = (p >> UB) & 3, v = p >> (UB + 2);
    int orig = (g << (UB + 2)) | (v << UB) | uo;
    bp[p] = b1[orig] + b2[orig];
  }
}

// ---------- input-projection GEMM: out[m,n] = sum_k A[m,k]*W[n,k] + bias[n] (bf16 in, bf16 out) ----------
// 64x64 tile, 256 thr = 4 waves; wave v computes rows [v*16, v*16+16) x 64 cols.
template<int KTOT, bool ENC_MAP>
__global__ __launch_bounds__(256, 1) void k_xproj(const u16* __restrict__ A, const u16* __restrict__ W,
                                                  const float* __restrict__ bias, u16* __restrict__ outp, int N){
  __shared__ u16 As[64][72];
  __shared__ u16 Ws[64][72];
  const int tid = threadIdx.x, l = tid & 63, v = tid >> 6;
  const int lb = l & 15, lq = l >> 4;
  const int m0 = blockIdx.x * 64, n0 = blockIdx.y * 64;
  f32x4 acc[4];
#pragma unroll
  for (int nt = 0; nt < 4; nt++){ float bv = bias[n0 + nt * 16 + lb]; f32x4 t = {bv, bv, bv, bv}; acc[nt] = t; }
  const int r = tid >> 3, c8 = (tid & 7) * 8;
  for (int kb = 0; kb < KTOT / 64; ++kb){
    __syncthreads();
    *(bf16x8*)&As[r][c8]      = *(const bf16x8*)&A[(size_t)(m0 + r) * KTOT + kb * 64 + c8];
    *(bf16x8*)&As[r + 32][c8] = *(const bf16x8*)&A[(size_t)(m0 + r + 32) * KTOT + kb * 64 + c8];
    *(bf16x8*)&Ws[r][c8]      = *(const bf16x8*)&W[(size_t)(n0 + r) * KTOT + kb * 64 + c8];
    *(bf16x8*)&Ws[r + 32][c8] = *(const bf16x8*)&W[(size_t)(n0 + r + 32) * KTOT + kb * 64 + c8];
    __syncthreads();
#pragma unroll
    for (int kc = 0; kc < 2; kc++){
      bf16x8 af = *(const bf16x8*)&As[v * 16 + lb][kc * 32 + lq * 8];
#pragma unroll
      for (int nt = 0; nt < 4; nt++){
        bf16x8 wf = *(const bf16x8*)&Ws[nt * 16 + lb][kc * 32 + lq * 8];
        acc[nt] = __builtin_amdgcn_mfma_f32_16x16x32_bf16(af, wf, acc[nt], 0, 0, 0);
      }
    }
  }
#pragma unroll
  for (int nt = 0; nt < 4; nt++){
    const int n = n0 + nt * 16 + lb;
#pragma unroll
    for (int j = 0; j < 4; j++){
      const int m = m0 + v * 16 + lq * 4 + j;
      size_t o;
      if (ENC_MAP) o = ((size_t)(m & 255) * 256 + (size_t)(m >> 8)) * (size_t)N + n; // m=b*T+t -> [t][b][N]
      else         o = (size_t)m * (size_t)N + n;                                    // m=t*B+b -> [t][b][N]
      outp[o] = (u16)f2bf_bits(acc[nt][j]);
    }
  }
}

// ---------- persistent recurrence ----------
// Grid 32, block 256 (4 waves, 1 wave/SIMD). wg owns batch slice of 8 (cols 8..15 of MFMA N are dead).
// Weights = A operand (M=gate rows), h = B operand (N=batch). Wave v owns rows [v*NMT*16,(v+1)*NMT*16).
// A-frag idx = kc*NMT+mt: [0,F_REG) in VGPRs, [F_REG,F_REG+F_LDS) in LDS, rest re-read from L2 each step.
template<int KDIM, int NMT, int NKC, int NQ, int F_REG, int F_LDS, bool IS_DEC>
__global__ __launch_bounds__(256, 1) void k_rec(const u16* __restrict__ Wp, const u16* __restrict__ xp,
                                                u16* __restrict__ enc_out, float* __restrict__ out){
  constexpr int NROWS = NMT * 64;      // 4H total gate rows
  constexpr int HP = KDIM + 8;         // padded h row (bank-conflict free b128 reads)
  static_assert(NMT == 4 * NQ, "tiles = 4 gates x NQ unit groups");
  __shared__ u16 h_lds[16][HP];
  __shared__ u16 a_lds[4][(F_LDS > 0) ? F_LDS : 1][512];
  const int tid = threadIdx.x;
  const int l = tid & 63, v = tid >> 6;
  const int lb = l & 15, lq = l >> 4;
  const int b0 = blockIdx.x * 8;

  // resident A-frags (one-time load; A[m=lane&15][k=quad*8+j])
  bf16x8 Areg[F_REG];
#pragma unroll
  for (int kc = 0; kc < NKC; ++kc)
#pragma unroll
    for (int mt = 0; mt < NMT; ++mt){
      const int idx = kc * NMT + mt;
      const u16* src = Wp + (size_t)(v * (NMT * 16) + mt * 16 + lb) * KDIM + kc * 32 + lq * 8;
      if (idx < F_REG) Areg[idx] = *(const bf16x8*)src;
      else if (idx < F_REG + F_LDS) *(bf16x8*)&a_lds[v][idx - F_REG][l * 8] = *(const bf16x8*)src;
    }
  for (int i = tid; i < 16 * HP; i += 256) (&h_lds[0][0])[i] = 0;  // h(-1)=0; rows 8..15 stay 0 forever
  float c[NQ][4];
#pragma unroll
  for (int q = 0; q < NQ; q++)
#pragma unroll
    for (int j = 0; j < 4; j++) c[q][j] = 0.f;
  __syncthreads();

  for (int t = 0; t < T_N; ++t){
    bf16x8 Bh[NKC];                     // B[k=quad*8+j][n=lane&15] = h[b=n][k]
#pragma unroll
    for (int kc = 0; kc < NKC; kc++) Bh[kc] = *(const bf16x8*)&h_lds[lb][kc * 32 + lq * 8];
    __syncthreads();                    // all waves have h(t-1) in regs before anyone overwrites
#pragma unroll
    for (int q = 0; q < NQ; ++q){
      f32x4 acc[4];
      if (lb < 8){
#pragma unroll
        for (int g = 0; g < 4; ++g){    // acc init = xp (bias+input proj), 4 consecutive permuted rows
          const int mt = g * NQ + q;
          const u16* xptr = xp + (size_t)(t * 256 + b0 + lb) * NROWS + v * (NMT * 16) + mt * 16 + lq * 4;
          uint2 rx = *(const uint2*)xptr;
          acc[g][0] = bflo(rx.x); acc[g][1] = bfhi(rx.x); acc[g][2] = bflo(rx.y); acc[g][3] = bfhi(rx.y);
        }
      } else {
#pragma unroll
        for (int g = 0; g < 4; ++g){ f32x4 z = {0.f, 0.f, 0.f, 0.f}; acc[g] = z; }
      }
#pragma unroll
      for (int kc = 0; kc < NKC; ++kc){
#pragma unroll
        for (int g = 0; g < 4; ++g){
          const int mt = g * NQ + q;
          const int idx = kc * NMT + mt;
          bf16x8 af;
          if (idx < F_REG) af = Areg[idx];
          else if (idx < F_REG + F_LDS) af = *(const bf16x8*)&a_lds[v][idx - F_REG][l * 8];
          else af = *(const bf16x8*)(Wp + (size_t)(v * (NMT * 16) + mt * 16 + lb) * KDIM + kc * 32 + lq * 8);
          acc[g] = __builtin_amdgcn_mfma_f32_16x16x32_bf16(af, Bh[kc], acc[g], 0, 0, 0);
        }
      }
      // fused gates: acc[0..3] = i,f,g,o pre-acts for same (b,u) per lane/reg
      float hv[4];
#pragma unroll
      for (int j = 0; j < 4; ++j){
        float iv = sigm(acc[0][j]);
        float fv = sigm(acc[1][j]);
        float gv = tanh_f(acc[2][j]);
        float ov = sigm(acc[3][j]);
        float cc = fv * c[q][j] + iv * gv;
        c[q][j] = cc;
        hv[j] = ov * tanh_f(cc);
      }
      if (lb < 8){
        const int u0 = v * (NQ * 16) + q * 16 + lq * 4;
        uint2 hp; hp.x = pack2(hv[0], hv[1]); hp.y = pack2(hv[2], hv[3]);
        *(uint2*)&h_lds[lb][u0] = hp;
        if (!IS_DEC){
          *(uint2*)(enc_out + (size_t)(t * 256 + b0 + lb) * KDIM + u0) = hp;       // encoded [T][B][H] bf16
        } else {
          float4 o4 = make_float4(hv[0], hv[1], hv[2], hv[3]);
          *(float4*)(out + ((size_t)(b0 + lb) * T_N + t) * D_N + u0) = o4;         // out [B][T][D] fp32
        }
      }
    }
    __syncthreads();                    // h(t) complete before next step's Bh loads
  }
}

extern "C" void kernel_launch(void* const* d_in, const int* in_sizes, int n_in,
                              void* d_out, int out_size, void* d_ws, size_t ws_size,
                              hipStream_t stream){
  const float* x    = (const float*)d_in[0];
  const float* eWih = (const float*)d_in[1];
  const float* eWhh = (const float*)d_in[2];
  const float* ebih = (const float*)d_in[3];
  const float* ebhh = (const float*)d_in[4];
  const float* dWih = (const float*)d_in[5];
  const float* dWhh = (const float*)d_in[6];
  const float* dbih = (const float*)d_in[7];
  const float* dbhh = (const float*)d_in[8];
  float* out = (float*)d_out;

  char* w = (char*)d_ws;
  size_t off = 0;
  auto carve = [&](size_t bytes) -> void* { void* p = w + off; off = (off + bytes + 255) & ~(size_t)255; return p; };
  u16*   xb    = (u16*)carve((size_t)B_N * T_N * D_N * 2);          // x in bf16
  u16*   WihEp = (u16*)carve((size_t)4 * H_N * D_N * 2);            // permuted enc Wih
  u16*   WhhEp = (u16*)carve((size_t)4 * H_N * H_N * 2);            // permuted enc Whh
  u16*   WihDp = (u16*)carve((size_t)4 * D_N * H_N * 2);            // permuted dec Wih
  u16*   WhhDp = (u16*)carve((size_t)4 * D_N * D_N * 2);            // permuted dec Whh
  float* bE    = (float*)carve((size_t)4 * H_N * 4);
  float* bD    = (float*)carve((size_t)4 * D_N * 4);
  u16*   xpE   = (u16*)carve((size_t)T_N * B_N * 4 * H_N * 2);      // [T][B][4H] permuted, bf16
  u16*   enc   = (u16*)carve((size_t)T_N * B_N * H_N * 2);          // encoded [T][B][H] bf16
  u16*   xpD   = (u16*)carve((size_t)T_N * B_N * 4 * D_N * 2);      // [T][B][4D] permuted, bf16
  (void)ws_size; (void)in_sizes; (void)n_in; (void)out_size;

  hipLaunchKernelGGL(k_cvt, dim3((B_N * T_N * D_N) / 1024), dim3(256), 0, stream, x, xb, B_N * T_N * D_N);
  hipLaunchKernelGGL(k_permW, dim3(1024), dim3(128), 0, stream, eWih, WihEp, 128, 6);
  hipLaunchKernelGGL(k_permW, dim3(1024), dim3(128), 0, stream, eWhh, WhhEp, 256, 6);
  hipLaunchKernelGGL(k_permW, dim3(512),  dim3(128), 0, stream, dWih, WihDp, 256, 5);
  hipLaunchKernelGGL(k_permW, dim3(512),  dim3(128), 0, stream, dWhh, WhhDp, 128, 5);
  hipLaunchKernelGGL(k_permB, dim3(1), dim3(256), 0, stream, ebih, ebhh, bE, 1024, 6);
  hipLaunchKernelGGL(k_permB, dim3(1), dim3(256), 0, stream, dbih, dbhh, bD, 512, 5);

  // enc x-proj: [65536,1024] = xb @ WihEp^T  (M rows are b*T+t -> stored [t][b][p])
  hipLaunchKernelGGL((k_xproj<128, true>),  dim3(1024, 16), dim3(256), 0, stream, xb,  WihEp, bE, xpE, 1024);
  // enc recurrence: KDIM=256, 16 Mtiles x 8 kchunks, 92 reg frags + 13 LDS + 23 L2-streamed
  hipLaunchKernelGGL((k_rec<256, 16, 8, 4, 92, 13, false>), dim3(32), dim3(256), 0, stream,
                     WhhEp, xpE, enc, (float*)nullptr);
  // dec x-proj: [65536,512] = enc @ WihDp^T (M rows are t*B+b -> stored [t][b][p])
  hipLaunchKernelGGL((k_xproj<256, false>), dim3(1024, 8),  dim3(256), 0, stream, enc, WihDp, bD, xpD, 512);
  // dec recurrence: KDIM=128, 8 Mtiles x 4 kchunks, all 32 frags in regs; writes final fp32 output
  hipLaunchKernelGGL((k_rec<128, 8, 4, 2, 32, 0, true>),  dim3(32), dim3(256), 0, stream,
                     WhhDp, xpD, (u16*)nullptr, out);
}

// Round 3
// 1736.008 us; speedup vs baseline: 1.1684x; 1.1684x over previous
//
#include <hip/hip_runtime.h>
#include <stdint.h>

// LSTM autoencoder: B=256,T=256,D=128,H=256, gate order i,f,g,o.
// Phases: cvt/perm prep -> enc xproj GEMM -> enc recurrence (persistent, batch-sliced)
//         -> dec xproj GEMM -> dec recurrence.
// R1: recurrence — full on-chip weight residency (regs+LDS, no L2 streaming),
// double-buffered h (1 barrier/step), xp added post-MFMA (off critical path),
// global stores after the barrier. dec-rec: 8 waves (2/SIMD).
// R2 FIX: k_permW/k_permB took gate stride as 1<<(UB+2) (assumed 4 waves); dec-rec
// uses 8 waves (VB=3) so dec weights were scrambled. Now orig=(g<<(UB+VB))|(v<<UB)|uo.

#define B_N 256
#define T_N 256
#define D_N 128
#define H_N 256

typedef __attribute__((ext_vector_type(8))) short bf16x8;  // MFMA A/B frag (4 VGPRs)
typedef __attribute__((ext_vector_type(4))) float f32x4;   // MFMA C/D frag
typedef unsigned short u16;
typedef unsigned int u32;

__device__ __forceinline__ float bflo(u32 u){ return __uint_as_float(u << 16); }
__device__ __forceinline__ float bfhi(u32 u){ return __uint_as_float(u & 0xffff0000u); }
__device__ __forceinline__ u32 f2bf_bits(float f){ u32 u = __float_as_uint(f); return (u + 0x7fffu + ((u >> 16) & 1u)) >> 16; }
__device__ __forceinline__ u32 pack2(float lo, float hi){ return f2bf_bits(lo) | (f2bf_bits(hi) << 16); }
__device__ __forceinline__ float sigm(float x){ return __builtin_amdgcn_rcpf(1.f + __expf(-x)); }
__device__ __forceinline__ float tanh_f(float x){ return 1.f - 2.f * __builtin_amdgcn_rcpf(1.f + __expf(2.f * x)); }
__device__ __forceinline__ float xpj(uint2 r, int j){
  return j == 0 ? bflo(r.x) : j == 1 ? bfhi(r.x) : j == 2 ? bflo(r.y) : bfhi(r.y);
}

// ---------- prep kernels ----------
__global__ void k_cvt(const float* __restrict__ src, u16* __restrict__ dst, int n){
  int i = (blockIdx.x * blockDim.x + threadIdx.x) * 4;
  if (i >= n) return;
  float4 v = *(const float4*)(src + i);
  uint2 o; o.x = pack2(v.x, v.y); o.y = pack2(v.z, v.w);
  *(uint2*)(dst + i) = o;
}

// Row permutation p -> orig so that wave v (of 1<<VB waves) owns rows
// [v*4U,(v+1)*4U) = {i,f,g,o} x units[v*U,(v+1)*U), U = 1<<UB units/wave.
// p = (v << (UB+2)) | (g << UB) | uo  ;  orig = (g << (UB+VB)) | (v << UB) | uo
__global__ void k_permW(const float* __restrict__ W, u16* __restrict__ Wp, int K, int UB, int VB){
  int p = blockIdx.x;
  int uo = p & ((1 << UB) - 1), g = (p >> UB) & 3, v = p >> (UB + 2);
  int orig = (g << (UB + VB)) | (v << UB) | uo;
  for (int k = threadIdx.x; k < K; k += blockDim.x)
    Wp[(size_t)p * K + k] = (u16)f2bf_bits(W[(size_t)orig * K + k]);
}

__global__ void k_permB(const float* __restrict__ b1, const float* __restrict__ b2,
                        float* __restrict__ bp, int P, int UB, int VB){
  for (int p = threadIdx.x; p < P; p += blockDim.x){
    int uo = p & ((1 << UB) - 1), g = (p >> UB) & 3, v = p >> (UB + 2);
    int orig = (g << (UB + VB)) | (v << UB) | uo;
    bp[p] = b1[orig] + b2[orig];
  }
}

// ---------- input-projection GEMM: out[m,n] = sum_k A[m,k]*W[n,k] + bias[n] (bf16 in, bf16 out) ----------
template<int KTOT, bool ENC_MAP>
__global__ __launch_bounds__(256, 1) void k_xproj(const u16* __restrict__ A, const u16* __restrict__ W,
                                                  const float* __restrict__ bias, u16* __restrict__ outp, int N){
  __shared__ u16 As[64][72];
  __shared__ u16 Ws[64][72];
  const int tid = threadIdx.x, l = tid & 63, v = tid >> 6;
  const int lb = l & 15, lq = l >> 4;
  const int m0 = blockIdx.x * 64, n0 = blockIdx.y * 64;
  f32x4 acc[4];
#pragma unroll
  for (int nt = 0; nt < 4; nt++){ float bv = bias[n0 + nt * 16 + lb]; f32x4 t = {bv, bv, bv, bv}; acc[nt] = t; }
  const int r = tid >> 3, c8 = (tid & 7) * 8;
  for (int kb = 0; kb < KTOT / 64; ++kb){
    __syncthreads();
    *(bf16x8*)&As[r][c8]      = *(const bf16x8*)&A[(size_t)(m0 + r) * KTOT + kb * 64 + c8];
    *(bf16x8*)&As[r + 32][c8] = *(const bf16x8*)&A[(size_t)(m0 + r + 32) * KTOT + kb * 64 + c8];
    *(bf16x8*)&Ws[r][c8]      = *(const bf16x8*)&W[(size_t)(n0 + r) * KTOT + kb * 64 + c8];
    *(bf16x8*)&Ws[r + 32][c8] = *(const bf16x8*)&W[(size_t)(n0 + r + 32) * KTOT + kb * 64 + c8];
    __syncthreads();
#pragma unroll
    for (int kc = 0; kc < 2; kc++){
      bf16x8 af = *(const bf16x8*)&As[v * 16 + lb][kc * 32 + lq * 8];
#pragma unroll
      for (int nt = 0; nt < 4; nt++){
        bf16x8 wf = *(const bf16x8*)&Ws[nt * 16 + lb][kc * 32 + lq * 8];
        acc[nt] = __builtin_amdgcn_mfma_f32_16x16x32_bf16(af, wf, acc[nt], 0, 0, 0);
      }
    }
  }
#pragma unroll
  for (int nt = 0; nt < 4; nt++){
    const int n = n0 + nt * 16 + lb;
#pragma unroll
    for (int j = 0; j < 4; j++){
      const int m = m0 + v * 16 + lq * 4 + j;
      size_t o;
      if (ENC_MAP) o = ((size_t)(m & 255) * 256 + (size_t)(m >> 8)) * (size_t)N + n; // m=b*T+t -> [t][b][N]
      else         o = (size_t)m * (size_t)N + n;                                    // m=t*B+b -> [t][b][N]
      outp[o] = (u16)f2bf_bits(acc[nt][j]);
    }
  }
}

// ---------- persistent recurrence ----------
// Grid 32 wgs; wg owns batch slice of 8 (MFMA N-cols 8..15 dead). Weights = A operand
// (M = gate rows, pre-permuted), h = B operand (N = batch). Wave v owns rows
// [v*NMT*16, (v+1)*NMT*16). Frag idx = kc*NMT+mt: [0,F_REG) in regs, rest in per-wave
// LDS. Full residency: F_REG+F_LDS == NMT*NKC (no L2 streaming).
// h double-buffered in LDS: read buf (t&1), write buf (t&1)^1, ONE barrier per step.
template<int KDIM, int NWAVE, int NMT, int NKC, int NQ, int F_REG, int F_LDS, bool IS_DEC>
__global__ __launch_bounds__(NWAVE * 64, 1) void k_rec(const u16* __restrict__ Wp, const u16* __restrict__ xp,
                                                       u16* __restrict__ enc_out, float* __restrict__ out){
  constexpr int NROWS = NWAVE * NMT * 16;   // total gate rows (4*Hout)
  constexpr int HP = KDIM + 8;              // padded h row (breaks 512B-stride bank aliasing)
  static_assert(NMT == 4 * NQ, "tiles = 4 gates x NQ unit groups");
  static_assert(F_REG + F_LDS == NMT * NKC, "full on-chip residency");
  extern __shared__ u16 smem[];
  u16* hbuf = smem;                          // [2][8][HP]
  u16* al   = smem + 2 * 8 * HP;             // [NWAVE][F_LDS][512]
  const int tid = threadIdx.x, l = tid & 63, v = tid >> 6;
  const int lb = l & 15, lq = l >> 4;
  const int b0 = blockIdx.x * 8;
  const u16* wwave = Wp + (size_t)(v * (NMT * 16) + lb) * KDIM + lq * 8;
  u16* alw = al + (size_t)v * F_LDS * 512;

  // one-time weight load: frag layout A[m=lane&15][k=quad*8+j]
  bf16x8 Areg[(F_REG > 0) ? F_REG : 1];
#pragma unroll
  for (int kc = 0; kc < NKC; ++kc)
#pragma unroll
    for (int mt = 0; mt < NMT; ++mt){
      const int idx = kc * NMT + mt;
      const u16* src = wwave + (size_t)(mt * 16) * KDIM + kc * 32;
      if (idx < F_REG) Areg[idx] = *(const bf16x8*)src;
      else             *(bf16x8*)&alw[(idx - F_REG) * 512 + l * 8] = *(const bf16x8*)src;
    }
  for (int i = tid; i < 8 * HP; i += NWAVE * 64) hbuf[i] = 0;   // h(-1) = 0 (buf 0)
  float c[NQ][4];
#pragma unroll
  for (int q = 0; q < NQ; q++)
#pragma unroll
    for (int j = 0; j < 4; j++) c[q][j] = 0.f;
  __syncthreads();

  const bf16x8 bz = {0, 0, 0, 0, 0, 0, 0, 0};
  for (int t = 0; t < T_N; ++t){
    const u16* xpt = xp + ((size_t)(t * 256 + b0 + lb)) * NROWS + v * (NMT * 16) + lq * 4;
    const u16* hrd = hbuf + (size_t)(t & 1) * (8 * HP);
    u16*       hwr = hbuf + (size_t)((t & 1) ^ 1) * (8 * HP);

    // xp software pipeline: load q=0 now, q+1 during q's MFMAs; consumed post-MFMA.
    uint2 xr_cur[4], xr_nxt[4];
#pragma unroll
    for (int g = 0; g < 4; ++g){
      uint2 z; z.x = 0; z.y = 0;
      if (lb < 8) z = *(const uint2*)(xpt + (size_t)(g * NQ) * 16);
      xr_cur[g] = z;
    }
    // h(t-1) B-frags: B[k=quad*8+j][n=lane&15] = h[b=n][k]; cols n>=8 unused -> zero
    bf16x8 Bh[NKC];
#pragma unroll
    for (int kc = 0; kc < NKC; ++kc)
      Bh[kc] = (lb < 8) ? *(const bf16x8*)&hrd[lb * HP + kc * 32 + lq * 8] : bz;

    uint2  hsv[NQ];   // packed h for post-barrier global store (enc)
    float4 osv[NQ];   // fp32 out for post-barrier global store (dec)
#pragma unroll
    for (int q = 0; q < NQ; ++q){
      if (q + 1 < NQ){
#pragma unroll
        for (int g = 0; g < 4; ++g){
          uint2 z; z.x = 0; z.y = 0;
          if (lb < 8) z = *(const uint2*)(xpt + (size_t)(g * NQ + q + 1) * 16);
          xr_nxt[g] = z;
        }
      }
      f32x4 acc[4];
#pragma unroll
      for (int g = 0; g < 4; ++g){ f32x4 zz = {0.f, 0.f, 0.f, 0.f}; acc[g] = zz; }
#pragma unroll
      for (int kc = 0; kc < NKC; ++kc)
#pragma unroll
        for (int g = 0; g < 4; ++g){
          const int idx = kc * NMT + g * NQ + q;
          bf16x8 af;
          if (idx < F_REG) af = Areg[idx];
          else             af = *(const bf16x8*)&alw[(idx - F_REG) * 512 + l * 8];
          acc[g] = __builtin_amdgcn_mfma_f32_16x16x32_bf16(af, Bh[kc], acc[g], 0, 0, 0);
        }
      // gates: acc[0..3] + xp = i,f,g,o pre-acts for same (b,u) per lane/reg
      float hv[4];
#pragma unroll
      for (int j = 0; j < 4; ++j){
        float iv = sigm(acc[0][j] + xpj(xr_cur[0], j));
        float fv = sigm(acc[1][j] + xpj(xr_cur[1], j));
        float gv = tanh_f(acc[2][j] + xpj(xr_cur[2], j));
        float ov = sigm(acc[3][j] + xpj(xr_cur[3], j));
        float cc = fv * c[q][j] + iv * gv;
        c[q][j] = cc;
        hv[j] = ov * tanh_f(cc);
      }
      if (lb < 8){
        const int u0 = v * (NQ * 16) + q * 16 + lq * 4;
        uint2 hp; hp.x = pack2(hv[0], hv[1]); hp.y = pack2(hv[2], hv[3]);
        *(uint2*)&hwr[lb * HP + u0] = hp;
        if (!IS_DEC) hsv[q] = hp;
        else         osv[q] = make_float4(hv[0], hv[1], hv[2], hv[3]);
      }
#pragma unroll
      for (int g = 0; g < 4; ++g) xr_cur[g] = xr_nxt[g];
    }
    __syncthreads();   // h(t) visible; global stores AFTER so vmcnt drain overlaps next step
    if (lb < 8){
#pragma unroll
      for (int q = 0; q < NQ; ++q){
        const int u0 = v * (NQ * 16) + q * 16 + lq * 4;
        if (!IS_DEC) *(uint2*)(enc_out + (size_t)(t * 256 + b0 + lb) * KDIM + u0) = hsv[q];
        else         *(float4*)(out + ((size_t)(b0 + lb) * T_N + t) * D_N + u0) = osv[q];
      }
    }
  }
}

extern "C" void kernel_launch(void* const* d_in, const int* in_sizes, int n_in,
                              void* d_out, int out_size, void* d_ws, size_t ws_size,
                              hipStream_t stream){
  const float* x    = (const float*)d_in[0];
  const float* eWih = (const float*)d_in[1];
  const float* eWhh = (const float*)d_in[2];
  const float* ebih = (const float*)d_in[3];
  const float* ebhh = (const float*)d_in[4];
  const float* dWih = (const float*)d_in[5];
  const float* dWhh = (const float*)d_in[6];
  const float* dbih = (const float*)d_in[7];
  const float* dbhh = (const float*)d_in[8];
  float* out = (float*)d_out;

  char* w = (char*)d_ws;
  size_t off = 0;
  auto carve = [&](size_t bytes) -> void* { void* p = w + off; off = (off + bytes + 255) & ~(size_t)255; return p; };
  u16*   xb    = (u16*)carve((size_t)B_N * T_N * D_N * 2);          // x in bf16
  u16*   WihEp = (u16*)carve((size_t)4 * H_N * D_N * 2);            // permuted enc Wih (UB=6,VB=2)
  u16*   WhhEp = (u16*)carve((size_t)4 * H_N * H_N * 2);            // permuted enc Whh (UB=6,VB=2)
  u16*   WihDp = (u16*)carve((size_t)4 * D_N * H_N * 2);            // permuted dec Wih (UB=4,VB=3)
  u16*   WhhDp = (u16*)carve((size_t)4 * D_N * D_N * 2);            // permuted dec Whh (UB=4,VB=3)
  float* bE    = (float*)carve((size_t)4 * H_N * 4);
  float* bD    = (float*)carve((size_t)4 * D_N * 4);
  u16*   xpE   = (u16*)carve((size_t)T_N * B_N * 4 * H_N * 2);      // [T][B][4H] permuted, bf16
  u16*   enc   = (u16*)carve((size_t)T_N * B_N * H_N * 2);          // encoded [T][B][H] bf16
  u16*   xpD   = (u16*)carve((size_t)T_N * B_N * 4 * D_N * 2);      // [T][B][4D] permuted, bf16
  (void)ws_size; (void)in_sizes; (void)n_in; (void)out_size;

  hipLaunchKernelGGL(k_cvt, dim3((B_N * T_N * D_N) / 1024), dim3(256), 0, stream, x, xb, B_N * T_N * D_N);
  hipLaunchKernelGGL(k_permW, dim3(1024), dim3(128), 0, stream, eWih, WihEp, 128, 6, 2);
  hipLaunchKernelGGL(k_permW, dim3(1024), dim3(128), 0, stream, eWhh, WhhEp, 256, 6, 2);
  hipLaunchKernelGGL(k_permW, dim3(512),  dim3(128), 0, stream, dWih, WihDp, 256, 4, 3);
  hipLaunchKernelGGL(k_permW, dim3(512),  dim3(128), 0, stream, dWhh, WhhDp, 128, 4, 3);
  hipLaunchKernelGGL(k_permB, dim3(1), dim3(256), 0, stream, ebih, ebhh, bE, 1024, 6, 2);
  hipLaunchKernelGGL(k_permB, dim3(1), dim3(256), 0, stream, dbih, dbhh, bD, 512, 4, 3);

  // enc x-proj: [65536,1024] = xb @ WihEp^T  (M rows are b*T+t -> stored [t][b][p])
  hipLaunchKernelGGL((k_xproj<128, true>),  dim3(1024, 16), dim3(256), 0, stream, xb,  WihEp, bE, xpE, 1024);
  // enc recurrence: 4 waves, 16 Mtiles x 8 kc, 91 reg frags + 37 LDS frags (zero streaming)
  // LDS: 2*8*264*2 + 4*37*1024 = 160000 B
  hipLaunchKernelGGL((k_rec<256, 4, 16, 8, 4, 91, 37, false>), dim3(32), dim3(256),
                     2 * 8 * (H_N + 8) * 2 + 4 * 37 * 1024, stream, WhhEp, xpE, enc, (float*)nullptr);
  // dec x-proj: [65536,512] = enc @ WihDp^T (M rows are t*B+b -> stored [t][b][N])
  hipLaunchKernelGGL((k_xproj<256, false>), dim3(1024, 8),  dim3(256), 0, stream, enc, WihDp, bD, xpD, 512);
  // dec recurrence: 8 waves (2/SIMD), 4 Mtiles x 4 kc, all 16 frags in regs; fp32 out
  hipLaunchKernelGGL((k_rec<128, 8, 4, 4, 1, 16, 0, true>),  dim3(32), dim3(512),
                     2 * 8 * (D_N + 8) * 2, stream, WhhDp, xpD, (u16*)nullptr, out);
}